// Round 7
// baseline (126.053 us; speedup 1.0000x reference)
//
#include <hip/hip_runtime.h>
#include <math.h>

#define Bc 8
#define Hc 128
#define Wc 128
#define Cc 20
#define Gc 64
#define HWc (Hc*Wc)          // 16384
#define NBLK (Bc*HWc/256)    // 2048 main blocks

// per-image workspace layout (floats), stride WS_STRIDE
//  box4[64] (by1,bx1,by2,bx2) AoS at 0..255
//  red4[64] (fgy,fgx,0.5/sy,0.5/sx) class-sorted AoS at 256..511
//  kpix int[64] class-sorted at 512; seg int[64] orig order at 576
//  starts int[22] at 640; nv f at 704; acc f[6] at 705; slice int at 712
//  global block counter at image-0 slot 713
#define WS_STRIDE 768
#define OFF_BOX   0
#define OFF_RED   256
#define OFF_KPIX  512
#define OFF_SEG   576
#define OFF_START 640
#define WS_NV     704
#define WS_ACC    705
#define WS_SLICE  712
#define WS_CNT    713

__global__ __launch_bounds__(64) void prep_kernel(
    const float* __restrict__ gt, const float* __restrict__ sy,
    const float* __restrict__ sx, float* __restrict__ ws)
{
  const int b = blockIdx.x;
  const int g = threadIdx.x;
  const float* row = gt + (size_t)(b*Gc + g)*7;
  const float cy = row[0];
  const float cx = row[1];

  // wave argmin over cy with first-index tie-break (== jnp.argmin)
  float v = cy; int idx = g;
  #pragma unroll
  for (int o = 32; o > 0; o >>= 1) {
    const float ov = __shfl_down(v, o, 64);
    const int   oi = __shfl_down(idx, o, 64);
    if (ov < v || (ov == v && oi < idx)) { v = ov; idx = oi; }
  }
  const int slice = __shfl(idx, 0, 64);
  const bool valid = g < slice;
  const int cid = (int)row[6] - 1;
  const int cls = (cid >= 0 && cid < Cc) ? cid : Cc;   // bucket 20 = bad class

  __shared__ int counts[Cc+1], offs[Cc+1], starts[Cc+2];
  if (g < Cc+1) { counts[g] = 0; offs[g] = 0; }
  __syncthreads();
  if (valid) atomicAdd(&counts[cls], 1);
  __syncthreads();
  if (g == 0) {
    int acc = 0;
    for (int c = 0; c < Cc+1; ++c) { starts[c] = acc; acc += counts[c]; }
    starts[Cc+1] = acc;
  }
  __syncthreads();

  float* wb = ws + (size_t)b*WS_STRIDE;
  int*  wbi = (int*)wb;
  float4 bx;
  bx.x = (row[2]+0.5f)*0.25f;  // by1
  bx.y = (row[3]+0.5f)*0.25f;  // bx1
  bx.z = (row[4]+0.5f)*0.25f;  // by2
  bx.w = (row[5]+0.5f)*0.25f;  // bx2
  ((float4*)(wb + OFF_BOX))[g] = bx;
  wbi[OFF_SEG+g] = (valid && cls < Cc) ? cls : Cc;
  if (valid) {
    const int pos = starts[cls] + atomicAdd(&offs[cls], 1);  // bucket order irrelevant (max/or)
    float4 rp;
    rp.x = floorf((cy+0.5f)*0.25f);
    rp.y = floorf((cx+0.5f)*0.25f);
    rp.z = 0.5f / sy[b*Gc+g];   // 0.5 factor folded in (red arg = -(dy^2*z + dx^2*w))
    rp.w = 0.5f / sx[b*Gc+g];
    ((float4*)(wb + OFF_RED))[pos] = rp;
    int kpy = (int)floorf(cy*0.25f); kpy = kpy < 0 ? 0 : (kpy > Hc-1 ? Hc-1 : kpy);
    int kpx = (int)floorf(cx*0.25f); kpx = kpx < 0 ? 0 : (kpx > Wc-1 ? Wc-1 : kpx);
    wbi[OFF_KPIX+pos] = kpy*Wc + kpx;
  }
  if (g < Cc+2) wbi[OFF_START+g] = starts[g];
  if (g == 0) { wb[WS_NV] = fmaxf((float)slice, 1.0f); wbi[WS_SLICE] = slice; }
  if (g < 6) wb[WS_ACC+g] = 0.0f;
  if (b == 0 && g == 0) ((int*)ws)[WS_CNT] = 0;
}

__device__ __forceinline__ float wave_sum(float v) {
  #pragma unroll
  for (int o = 32; o > 0; o >>= 1) v += __shfl_down(v, o, 64);
  return v;
}

__global__ __launch_bounds__(256, 4) void main_kernel(
  const float* __restrict__ kpt, const float* __restrict__ preg,
  const float* __restrict__ fpn, const float* __restrict__ masks,
  const float* __restrict__ wsc, float* __restrict__ wsa,
  float* __restrict__ out)
{
  __shared__ float s_part[4][6];

  const int tid = threadIdx.x;
  const int b   = blockIdx.x >> 6;
  const int pix = blockIdx.x*256 + tid;
  const int hw  = pix & (HWc-1);
  const int h = hw >> 7, w = hw & (Wc-1);

  const float* wb  = wsc + (size_t)b*WS_STRIDE;     // read-only view (scalar loads)
  const int*   wbi = (const int*)wb;
  const float4* __restrict__ box4 = (const float4*)(wb + OFF_BOX);
  const float4* __restrict__ red4 = (const float4*)(wb + OFF_RED);
  const int nslice = wbi[WS_SLICE];

  const float wx = w + 0.5f, hy = h + 0.5f;
  const float px_ = (float)w, py_ = (float)h;
  const float4* mrow4 = (const float4*)(masks + (size_t)pix*Gc);

  // ---- pass 1: full 8-chunks without per-element bound check, scalar tail ----
  float amin = 3.0e38f; float loc = 0.0f, mmin = 0.0f; int gmin = 0;
  const int nfull = nslice & ~7;
  float4 ma = mrow4[0], mb = mrow4[1];              // always in-bounds (row = 16 float4s)
  for (int g0 = 0; g0 < nfull; g0 += 8) {
    const int pf = (g0 + 8) < Gc ? ((g0 + 8) >> 2) : 14;   // clamped, unconditional
    const float4 na = mrow4[pf];
    const float4 nb = mrow4[pf + 1];
    #pragma unroll
    for (int j = 0; j < 8; ++j) {
      const int g = g0 + j;
      const float m = (j==0)?ma.x:(j==1)?ma.y:(j==2)?ma.z:(j==3)?ma.w
                    : (j==4)?mb.x:(j==5)?mb.y:(j==6)?mb.z:mb.w;
      const float4 bx = box4[g];                    // uniform addr -> scalar load
      const float dl = wx - bx.y, dr = bx.w - wx;
      const float dt = hy - bx.x, db = bx.z - hy;
      const bool inb = (dl > 0.f) & (dr > 0.f) & (dt > 0.f) & (db > 0.f);
      const float hm = inb ? m : 0.f;
      const float area = (dl*hm + dr*hm) * (dt*hm + db*hm);
      const float ap = area + (1.f - hm)*1e8f;
      if (ap < amin) { amin = ap; gmin = g; mmin = m; }
      loc = fmaxf(loc, hm);
    }
    ma = na; mb = nb;
  }
  for (int g = nfull; g < nslice; ++g) {            // tail (empty when NV%8==0)
    const float m = masks[(size_t)pix*Gc + g];
    const float4 bx = box4[g];
    const float dl = wx - bx.y, dr = bx.w - wx;
    const float dt = hy - bx.x, db = bx.z - hy;
    const bool inb = (dl > 0.f) & (dr > 0.f) & (dt > 0.f) & (db > 0.f);
    const float hm = inb ? m : 0.f;
    const float area = (dl*hm + dr*hm) * (dt*hm + db*hm);
    const float ap = area + (1.f - hm)*1e8f;
    if (ap < amin) { amin = ap; gmin = g; mmin = m; }
    loc = fmaxf(loc, hm);
  }

  // ---- dist_mask nonzero only at gmin (mmin tracked, no re-gather) ----
  float dlm=0.f, drm=0.f, dtm=0.f, dbm=0.f, hmval=0.f; int cmin = Cc;
  if (loc > 0.f) {
    const float4 bx = box4[gmin];
    const float dl = wx - bx.y, dr = bx.w - wx;
    const float dt = hy - bx.x, db = bx.z - hy;
    const float area = (dl*mmin + dr*mmin) * (dt*mmin + db*mmin);
    if (area == amin) {                             // unpadded==padded-min semantics
      dlm = dl*mmin*loc; drm = dr*mmin*loc; dtm = dt*mmin*loc; dbm = db*mmin*loc;
      cmin = wbi[OFF_SEG + gmin];
      hmval = loc;
    }
  }

  // ---- pass 2: class buckets. exp-of-max: fmax args per gt, ONE exp per class
  //      (v_exp_f32 monotonic => max(exp(a))==exp(max(a)); empty: exp(-1e30)=+0) ----
  const float4* kq4 = (const float4*)(kpt + (size_t)pix*Cc);
  const float4* fq4 = (const float4*)(fpn + (size_t)pix*Cc);
  float4 kcur = kq4[0], fcur = fq4[0];
  float gargmax = -1e30f, grav = 0.f, hneg = 0.f;
  int sb = wbi[OFF_START];
  for (int cg = 0; cg < 5; ++cg) {
    const int nx = cg < 4 ? cg + 1 : 4;             // clamped prefetch
    const float4 knxt = kq4[nx];
    const float4 fnxt = fq4[nx];
    #pragma unroll
    for (int j = 0; j < 4; ++j) {
      const int c = cg*4 + j;
      const int s1 = wbi[OFF_START + c + 1];
      float ramax = -1e30f; bool kpv = false;
      for (int i = sb; i < s1; ++i) {               // wave-uniform bounds
        const float4 rp = red4[i];                  // uniform -> s_load
        const int kpix = wbi[OFF_KPIX + i];
        const float dy = py_ - rp.x, dx = px_ - rp.y;
        const float arg = -(dy*dy*rp.z + dx*dx*rp.w);
        ramax = fmaxf(ramax, arg);
        kpv = kpv | (kpix == hw);
      }
      sb = s1;
      const float rmax = __expf(ramax);             // 0 exactly for empty bucket
      gargmax = fmaxf(gargmax, ramax);
      // shared-exp sigmoid + log-sigmoid
      const float x  = (j==0)?kcur.x:(j==1)?kcur.y:(j==2)?kcur.z:kcur.w;
      const float e  = __expf(-fabsf(x));
      const float t  = 1.f + e;
      const float r  = 1.f / t;
      const float L  = __logf(t);
      const float s  = (x >= 0.f) ? r : e*r;
      const float lsx = fminf(x, 0.f) - L;
      const float kv = kpv ? 1.f : 0.f;
      const float om = 1.f - rmax;
      const float om4 = (om*om)*(om*om);
      const float oms = 1.f - s;
      grav += (-(oms*oms)*lsx)*kv + (-om4*(s*s)*(lsx - x))*(1.f - kv);

      const float fx  = (j==0)?fcur.x:(j==1)?fcur.y:(j==2)?fcur.z:fcur.w;
      const float ef  = __expf(-fabsf(fx));
      const float tf  = 1.f + ef;
      const float rf  = 1.f / tf;
      const float Lf  = __logf(tf);
      const float sf  = (fx >= 0.f) ? rf : ef*rf;
      const float lsf = fminf(fx, 0.f) - Lf;
      hneg += -10.f*(sf*sf)*(lsf - fx);             // hg=0 baseline; fixed up below
    }
    kcur = knxt; fcur = fnxt;
  }
  {
    const int e20 = wbi[OFF_START + Cc + 1];
    for (int i = sb; i < e20; ++i) {                // bucket 20: iou_red arg only
      const float4 rp = red4[i];
      const float dy = py_ - rp.x, dx = px_ - rp.y;
      gargmax = fmaxf(gargmax, -(dy*dy*rp.z + dx*dx*rp.w));
    }
  }
  const float iou_red = __expf(gargmax);            // 0 exactly if no valid gts

  // ---- iou term ----
  const float4 p4 = *(const float4*)(preg + (size_t)pix*4);
  const float inter = (fminf(dlm,p4.x)+fminf(drm,p4.y)) * (fminf(dtm,p4.z)+fminf(dbm,p4.w));
  const float uni = (dlm+drm)*(dtm+dbm) + (p4.x+p4.y)*(p4.z+p4.w) - inter;
  const float iou = inter / (uni + 1e-12f);
  const float t_iou = -__logf(iou + 1e-12f) * loc * (iou_red*4.f + 1.f);

  // ---- hm fixup at cmin (reload single fpn element, L1-hot) ----
  float hpos = 0.f, shg = 0.f;
  if (hmval > 0.f && cmin < Cc) {
    const float fx  = fpn[(size_t)pix*Cc + cmin];
    const float ef  = __expf(-fabsf(fx));
    const float tf  = 1.f + ef;
    const float rf  = 1.f / tf;
    const float Lf  = __logf(tf);
    const float sf  = (fx >= 0.f) ? rf : ef*rf;
    const float lsf = fminf(fx, 0.f) - Lf;
    const float osf = 1.f - sf;
    hpos = -10.f*(osf*osf)*lsf*hmval;
    hneg -= (-10.f*(sf*sf)*(lsf - fx))*hmval;
    shg = hmval;
  }

  // ---- block reduction ----
  float v0 = wave_sum(t_iou);
  float v1 = wave_sum(loc);
  float v2 = wave_sum(grav);
  float v3 = wave_sum(hpos);
  float v4 = wave_sum(hneg);
  float v5 = wave_sum(shg);
  const int wv = tid >> 6, ln = tid & 63;
  if (ln == 0) {
    s_part[wv][0]=v0; s_part[wv][1]=v1; s_part[wv][2]=v2;
    s_part[wv][3]=v3; s_part[wv][4]=v4; s_part[wv][5]=v5;
  }
  __syncthreads();
  if (tid < 6) {
    const float a = s_part[0][tid] + s_part[1][tid] + s_part[2][tid] + s_part[3][tid];
    atomicAdd(wsa + (size_t)b*WS_STRIDE + WS_ACC + tid, a);
  }
  __syncthreads();

  // ---- last block finalizes: lane bb handles image bb, then wave-sum ----
  if (tid >= 64) return;
  bool last = false;
  if (tid == 0) {
    __threadfence();
    last = (atomicAdd(&((int*)wsa)[WS_CNT], 1) == NBLK - 1);
  }
  last = (bool)__shfl((int)last, 0, 64);
  if (last) {
    float total = 0.f;
    if (tid < Bc) {
      float* ab = wsa + (size_t)tid*WS_STRIDE;      // device-scope atomic reads (L2)
      const float iou_loss = atomicAdd(ab+WS_ACC+0, 0.f);
      const float s_loc    = atomicAdd(ab+WS_ACC+1, 0.f);
      const float gravs    = atomicAdd(ab+WS_ACC+2, 0.f);
      const float hposs    = atomicAdd(ab+WS_ACC+3, 0.f);
      const float hnegs    = atomicAdd(ab+WS_ACC+4, 0.f);
      const float shgs     = atomicAdd(ab+WS_ACC+5, 0.f);
      const float nv       = atomicAdd(ab+WS_NV,    0.f);
      const float hm_loss  = hnegs / ((float)(HWc*Cc) - shgs);
      const bool  cond     = (shgs != 0.0f);
      const float safe_hg  = cond ? shgs : 1.0f;
      const float safe_loc = (s_loc > 0.0f) ? s_loc : 1.0f;
      const float hm2      = hm_loss + hposs/safe_hg;
      total = cond ? (iou_loss/safe_loc + gravs/nv + hm2) : hm_loss;
    }
    total = wave_sum(total);
    if (tid == 0) out[0] = total * (1.0f/(float)Bc);
  }
}

extern "C" void kernel_launch(void* const* d_in, const int* in_sizes, int n_in,
                              void* d_out, int out_size, void* d_ws, size_t ws_size,
                              hipStream_t stream) {
  const float* kpt  = (const float*)d_in[0];  // keypoints  [B,H,W,C]
  const float* preg = (const float*)d_in[1];  // preg       [B,H,W,4]
  const float* fpn  = (const float*)d_in[2];  // fpn        [B,H,W,C]
  const float* gt   = (const float*)d_in[3];  // gt         [B,G,7]
  const float* mk   = (const float*)d_in[4];  // masks      [B,H,W,G]
  const float* sy   = (const float*)d_in[5];  // scalar_y   [B,G]
  const float* sx   = (const float*)d_in[6];  // scalar_x   [B,G]
  float* ws  = (float*)d_ws;
  float* out = (float*)d_out;

  prep_kernel<<<Bc, 64, 0, stream>>>(gt, sy, sx, ws);
  main_kernel<<<NBLK, 256, 0, stream>>>(kpt, preg, fpn, mk, ws, ws, out);
}

// Round 8
// 116.264 us; speedup vs baseline: 1.0842x; 1.0842x over previous
//
#include <hip/hip_runtime.h>
#include <math.h>

#define Bc 8
#define Hc 128
#define Wc 128
#define Cc 20
#define Gc 64
#define HWc (Hc*Wc)          // 16384
#define NBLK (Bc*HWc/256)    // 2048 main blocks

// per-image workspace layout (floats), stride WS_STRIDE
//  box4[64] (by1,bx1,by2,bx2) AoS at 0..255
//  red4[64] (fgy,fgx,0.5/sy,0.5/sx) class-sorted AoS at 256..511
//  kpix int[64] class-sorted at 512; seg int[64] orig order at 576
//  starts int[22] at 640; nv f at 704; acc f[6] at 705; slice int at 712
#define WS_STRIDE 768
#define OFF_BOX   0
#define OFF_RED   256
#define OFF_KPIX  512
#define OFF_SEG   576
#define OFF_START 640
#define WS_NV     704
#define WS_ACC    705
#define WS_SLICE  712

__global__ __launch_bounds__(64) void prep_kernel(
    const float* __restrict__ gt, const float* __restrict__ sy,
    const float* __restrict__ sx, float* __restrict__ ws)
{
  const int b = blockIdx.x;
  const int g = threadIdx.x;
  const float* row = gt + (size_t)(b*Gc + g)*7;
  const float cy = row[0];
  const float cx = row[1];

  // wave argmin over cy with first-index tie-break (== jnp.argmin)
  float v = cy; int idx = g;
  #pragma unroll
  for (int o = 32; o > 0; o >>= 1) {
    const float ov = __shfl_down(v, o, 64);
    const int   oi = __shfl_down(idx, o, 64);
    if (ov < v || (ov == v && oi < idx)) { v = ov; idx = oi; }
  }
  const int slice = __shfl(idx, 0, 64);
  const bool valid = g < slice;
  const int cid = (int)row[6] - 1;
  const int cls = (cid >= 0 && cid < Cc) ? cid : Cc;   // bucket 20 = bad class

  __shared__ int counts[Cc+1], offs[Cc+1], starts[Cc+2];
  if (g < Cc+1) { counts[g] = 0; offs[g] = 0; }
  __syncthreads();
  if (valid) atomicAdd(&counts[cls], 1);
  __syncthreads();
  if (g == 0) {
    int acc = 0;
    for (int c = 0; c < Cc+1; ++c) { starts[c] = acc; acc += counts[c]; }
    starts[Cc+1] = acc;
  }
  __syncthreads();

  float* wb = ws + (size_t)b*WS_STRIDE;
  int*  wbi = (int*)wb;
  float4 bx;
  bx.x = (row[2]+0.5f)*0.25f;  // by1
  bx.y = (row[3]+0.5f)*0.25f;  // bx1
  bx.z = (row[4]+0.5f)*0.25f;  // by2
  bx.w = (row[5]+0.5f)*0.25f;  // bx2
  ((float4*)(wb + OFF_BOX))[g] = bx;
  wbi[OFF_SEG+g] = (valid && cls < Cc) ? cls : Cc;
  if (valid) {
    const int pos = starts[cls] + atomicAdd(&offs[cls], 1);  // bucket order irrelevant (max/or)
    float4 rp;
    rp.x = floorf((cy+0.5f)*0.25f);
    rp.y = floorf((cx+0.5f)*0.25f);
    rp.z = 0.5f / sy[b*Gc+g];   // 0.5 factor folded in (red arg = -(dy^2*z + dx^2*w))
    rp.w = 0.5f / sx[b*Gc+g];
    ((float4*)(wb + OFF_RED))[pos] = rp;
    int kpy = (int)floorf(cy*0.25f); kpy = kpy < 0 ? 0 : (kpy > Hc-1 ? Hc-1 : kpy);
    int kpx = (int)floorf(cx*0.25f); kpx = kpx < 0 ? 0 : (kpx > Wc-1 ? Wc-1 : kpx);
    wbi[OFF_KPIX+pos] = kpy*Wc + kpx;
  }
  if (g < Cc+2) wbi[OFF_START+g] = starts[g];
  if (g == 0) { wb[WS_NV] = fmaxf((float)slice, 1.0f); wbi[WS_SLICE] = slice; }
  if (g < 6) wb[WS_ACC+g] = 0.0f;
}

__device__ __forceinline__ float wave_sum(float v) {
  #pragma unroll
  for (int o = 32; o > 0; o >>= 1) v += __shfl_down(v, o, 64);
  return v;
}

__global__ __launch_bounds__(256, 4) void main_kernel(
  const float* __restrict__ kpt, const float* __restrict__ preg,
  const float* __restrict__ fpn, const float* __restrict__ masks,
  const float* __restrict__ wsc, float* __restrict__ wsa)
{
  __shared__ float s_part[4][6];

  const int tid = threadIdx.x;
  const int b   = blockIdx.x >> 6;
  const int pix = blockIdx.x*256 + tid;
  const int hw  = pix & (HWc-1);
  const int h = hw >> 7, w = hw & (Wc-1);

  const float* wb  = wsc + (size_t)b*WS_STRIDE;     // read-only view (scalar loads)
  const int*   wbi = (const int*)wb;
  const float4* __restrict__ box4 = (const float4*)(wb + OFF_BOX);
  const float4* __restrict__ red4 = (const float4*)(wb + OFF_RED);
  const int nslice = wbi[WS_SLICE];

  const float wx = w + 0.5f, hy = h + 0.5f;
  const float px_ = (float)w, py_ = (float)h;
  const float4* mrow4 = (const float4*)(masks + (size_t)pix*Gc);

  // ---- pass 1: full 8-chunks without per-element bound check, scalar tail ----
  float amin = 3.0e38f; float loc = 0.0f, mmin = 0.0f; int gmin = 0;
  const int nfull = nslice & ~7;
  float4 ma = mrow4[0], mb = mrow4[1];              // always in-bounds (row = 16 float4s)
  for (int g0 = 0; g0 < nfull; g0 += 8) {
    const int pf = (g0 + 8) < Gc ? ((g0 + 8) >> 2) : 14;   // clamped, unconditional
    const float4 na = mrow4[pf];
    const float4 nb = mrow4[pf + 1];
    #pragma unroll
    for (int j = 0; j < 8; ++j) {
      const int g = g0 + j;
      const float m = (j==0)?ma.x:(j==1)?ma.y:(j==2)?ma.z:(j==3)?ma.w
                    : (j==4)?mb.x:(j==5)?mb.y:(j==6)?mb.z:mb.w;
      const float4 bx = box4[g];                    // uniform addr -> scalar load
      const float dl = wx - bx.y, dr = bx.w - wx;
      const float dt = hy - bx.x, db = bx.z - hy;
      const bool inb = (dl > 0.f) & (dr > 0.f) & (dt > 0.f) & (db > 0.f);
      const float hm = inb ? m : 0.f;
      const float area = (dl*hm + dr*hm) * (dt*hm + db*hm);
      const float ap = area + (1.f - hm)*1e8f;
      if (ap < amin) { amin = ap; gmin = g; mmin = m; }
      loc = fmaxf(loc, hm);
    }
    ma = na; mb = nb;
  }
  for (int g = nfull; g < nslice; ++g) {            // tail (empty when NV%8==0)
    const float m = masks[(size_t)pix*Gc + g];
    const float4 bx = box4[g];
    const float dl = wx - bx.y, dr = bx.w - wx;
    const float dt = hy - bx.x, db = bx.z - hy;
    const bool inb = (dl > 0.f) & (dr > 0.f) & (dt > 0.f) & (db > 0.f);
    const float hm = inb ? m : 0.f;
    const float area = (dl*hm + dr*hm) * (dt*hm + db*hm);
    const float ap = area + (1.f - hm)*1e8f;
    if (ap < amin) { amin = ap; gmin = g; mmin = m; }
    loc = fmaxf(loc, hm);
  }

  // ---- dist_mask nonzero only at gmin (mmin tracked, no re-gather) ----
  float dlm=0.f, drm=0.f, dtm=0.f, dbm=0.f, hmval=0.f; int cmin = Cc;
  if (loc > 0.f) {
    const float4 bx = box4[gmin];
    const float dl = wx - bx.y, dr = bx.w - wx;
    const float dt = hy - bx.x, db = bx.z - hy;
    const float area = (dl*mmin + dr*mmin) * (dt*mmin + db*mmin);
    if (area == amin) {                             // unpadded==padded-min semantics
      dlm = dl*mmin*loc; drm = dr*mmin*loc; dtm = dt*mmin*loc; dbm = db*mmin*loc;
      cmin = wbi[OFF_SEG + gmin];
      hmval = loc;
    }
  }

  // ---- pass 2: class buckets. exp-of-max: fmax args per gt, ONE exp per class
  //      (v_exp_f32 monotonic => max(exp(a))==exp(max(a)); empty: exp(-1e30)=+0) ----
  const float4* kq4 = (const float4*)(kpt + (size_t)pix*Cc);
  const float4* fq4 = (const float4*)(fpn + (size_t)pix*Cc);
  float4 kcur = kq4[0], fcur = fq4[0];
  float gargmax = -1e30f, grav = 0.f, hneg = 0.f;
  int sb = wbi[OFF_START];
  for (int cg = 0; cg < 5; ++cg) {
    const int nx = cg < 4 ? cg + 1 : 4;             // clamped prefetch
    const float4 knxt = kq4[nx];
    const float4 fnxt = fq4[nx];
    #pragma unroll
    for (int j = 0; j < 4; ++j) {
      const int c = cg*4 + j;
      const int s1 = wbi[OFF_START + c + 1];
      float ramax = -1e30f; bool kpv = false;
      for (int i = sb; i < s1; ++i) {               // wave-uniform bounds
        const float4 rp = red4[i];                  // uniform -> s_load
        const int kpix = wbi[OFF_KPIX + i];
        const float dy = py_ - rp.x, dx = px_ - rp.y;
        const float arg = -(dy*dy*rp.z + dx*dx*rp.w);
        ramax = fmaxf(ramax, arg);
        kpv = kpv | (kpix == hw);
      }
      sb = s1;
      const float rmax = __expf(ramax);             // 0 exactly for empty bucket
      gargmax = fmaxf(gargmax, ramax);
      // shared-exp sigmoid + log-sigmoid
      const float x  = (j==0)?kcur.x:(j==1)?kcur.y:(j==2)?kcur.z:kcur.w;
      const float e  = __expf(-fabsf(x));
      const float t  = 1.f + e;
      const float r  = 1.f / t;
      const float L  = __logf(t);
      const float s  = (x >= 0.f) ? r : e*r;
      const float lsx = fminf(x, 0.f) - L;
      const float kv = kpv ? 1.f : 0.f;
      const float om = 1.f - rmax;
      const float om4 = (om*om)*(om*om);
      const float oms = 1.f - s;
      grav += (-(oms*oms)*lsx)*kv + (-om4*(s*s)*(lsx - x))*(1.f - kv);

      const float fx  = (j==0)?fcur.x:(j==1)?fcur.y:(j==2)?fcur.z:fcur.w;
      const float ef  = __expf(-fabsf(fx));
      const float tf  = 1.f + ef;
      const float rf  = 1.f / tf;
      const float Lf  = __logf(tf);
      const float sf  = (fx >= 0.f) ? rf : ef*rf;
      const float lsf = fminf(fx, 0.f) - Lf;
      hneg += -10.f*(sf*sf)*(lsf - fx);             // hg=0 baseline; fixed up below
    }
    kcur = knxt; fcur = fnxt;
  }
  {
    const int e20 = wbi[OFF_START + Cc + 1];
    for (int i = sb; i < e20; ++i) {                // bucket 20: iou_red arg only
      const float4 rp = red4[i];
      const float dy = py_ - rp.x, dx = px_ - rp.y;
      gargmax = fmaxf(gargmax, -(dy*dy*rp.z + dx*dx*rp.w));
    }
  }
  const float iou_red = __expf(gargmax);            // 0 exactly if no valid gts

  // ---- iou term ----
  const float4 p4 = *(const float4*)(preg + (size_t)pix*4);
  const float inter = (fminf(dlm,p4.x)+fminf(drm,p4.y)) * (fminf(dtm,p4.z)+fminf(dbm,p4.w));
  const float uni = (dlm+drm)*(dtm+dbm) + (p4.x+p4.y)*(p4.z+p4.w) - inter;
  const float iou = inter / (uni + 1e-12f);
  const float t_iou = -__logf(iou + 1e-12f) * loc * (iou_red*4.f + 1.f);

  // ---- hm fixup at cmin (reload single fpn element, L1-hot) ----
  float hpos = 0.f, shg = 0.f;
  if (hmval > 0.f && cmin < Cc) {
    const float fx  = fpn[(size_t)pix*Cc + cmin];
    const float ef  = __expf(-fabsf(fx));
    const float tf  = 1.f + ef;
    const float rf  = 1.f / tf;
    const float Lf  = __logf(tf);
    const float sf  = (fx >= 0.f) ? rf : ef*rf;
    const float lsf = fminf(fx, 0.f) - Lf;
    const float osf = 1.f - sf;
    hpos = -10.f*(osf*osf)*lsf*hmval;
    hneg -= (-10.f*(sf*sf)*(lsf - fx))*hmval;
    shg = hmval;
  }

  // ---- block reduction ----
  float v0 = wave_sum(t_iou);
  float v1 = wave_sum(loc);
  float v2 = wave_sum(grav);
  float v3 = wave_sum(hpos);
  float v4 = wave_sum(hneg);
  float v5 = wave_sum(shg);
  const int wv = tid >> 6, ln = tid & 63;
  if (ln == 0) {
    s_part[wv][0]=v0; s_part[wv][1]=v1; s_part[wv][2]=v2;
    s_part[wv][3]=v3; s_part[wv][4]=v4; s_part[wv][5]=v5;
  }
  __syncthreads();
  if (tid < 6) {
    const float a = s_part[0][tid] + s_part[1][tid] + s_part[2][tid] + s_part[3][tid];
    atomicAdd(wsa + (size_t)b*WS_STRIDE + WS_ACC + tid, a);
  }
}

__global__ __launch_bounds__(64) void fin_kernel(const float* __restrict__ ws,
                                                 float* __restrict__ out)
{
  const int b = threadIdx.x;
  float total = 0.0f;
  if (b < Bc) {
    const float* wb = ws + (size_t)b*WS_STRIDE;
    const float iou_loss = wb[WS_ACC+0];
    const float s_loc    = wb[WS_ACC+1];
    const float grav     = wb[WS_ACC+2];
    const float hposs    = wb[WS_ACC+3];
    const float hnegs    = wb[WS_ACC+4];
    const float shg      = wb[WS_ACC+5];
    const float nv       = wb[WS_NV];
    const float hm_loss  = hnegs / ((float)(HWc*Cc) - shg);
    const bool  cond     = (shg != 0.0f);
    const float safe_hg  = cond ? shg : 1.0f;
    const float safe_loc = (s_loc > 0.0f) ? s_loc : 1.0f;
    const float hm2      = hm_loss + hposs/safe_hg;
    total = cond ? (iou_loss/safe_loc + grav/nv + hm2) : hm_loss;
  }
  #pragma unroll
  for (int o = 4; o > 0; o >>= 1) total += __shfl_down(total, o, 64);
  if (b == 0) out[0] = total * (1.0f/(float)Bc);
}

extern "C" void kernel_launch(void* const* d_in, const int* in_sizes, int n_in,
                              void* d_out, int out_size, void* d_ws, size_t ws_size,
                              hipStream_t stream) {
  const float* kpt  = (const float*)d_in[0];  // keypoints  [B,H,W,C]
  const float* preg = (const float*)d_in[1];  // preg       [B,H,W,4]
  const float* fpn  = (const float*)d_in[2];  // fpn        [B,H,W,C]
  const float* gt   = (const float*)d_in[3];  // gt         [B,G,7]
  const float* mk   = (const float*)d_in[4];  // masks      [B,H,W,G]
  const float* sy   = (const float*)d_in[5];  // scalar_y   [B,G]
  const float* sx   = (const float*)d_in[6];  // scalar_x   [B,G]
  float* ws  = (float*)d_ws;
  float* out = (float*)d_out;

  prep_kernel<<<Bc, 64, 0, stream>>>(gt, sy, sx, ws);
  main_kernel<<<NBLK, 256, 0, stream>>>(kpt, preg, fpn, mk, ws, ws);
  fin_kernel<<<1, 64, 0, stream>>>(ws, out);
}